// Round 10
// baseline (545.712 us; speedup 1.0000x reference)
//
#include <hip/hip_runtime.h>

// Problem constants
#define B_   4
#define C_   256
#define N_   4096   // H*W
#define D_   32     // qk projection dim
#define CP   264    // proj s_x row stride (halves): 256 + 8

typedef _Float16 half8  __attribute__((ext_vector_type(8)));
typedef _Float16 half4v __attribute__((ext_vector_type(4)));
typedef _Float16 half2v __attribute__((ext_vector_type(2)));
typedef float    f32x4  __attribute__((ext_vector_type(4)));

// ---------------------------------------------------------------------------
// Kernel 0: convert W (f32) -> Wh (f16), A-frag layout:
// Wh[((t*8+kc)*16 + row)*32 + kk] = W_t[row][kc*32+kk], t: 0-1 q, 2-3 k, 4-19 v
// ---------------------------------------------------------------------------
__global__ __launch_bounds__(256) void wcvt_kernel(
    const float* __restrict__ Wq, const float* __restrict__ Wk,
    const float* __restrict__ Wv, _Float16* __restrict__ Wh)
{
    const int idx = blockIdx.x * 256 + threadIdx.x;
    const int kk  = idx & 31;
    const int row = (idx >> 5) & 15;
    const int kc  = (idx >> 9) & 7;
    const int t   = idx >> 12;
    const int c   = kc*32 + kk;
    float v;
    if (t < 2)      v = Wq[(t*16 + row)*C_ + c];
    else if (t < 4) v = Wk[((t-2)*16 + row)*C_ + c];
    else            v = Wv[((t-4)*16 + row)*C_ + c];
    Wh[idx] = (_Float16)v;
}

// ---------------------------------------------------------------------------
// Kernel 1: projections v5 (unchanged from round 9).
// Vh2 layout (flash 16B/lane V loads): Vh2[b][jc2*8192 + ctg*512 + lr*8 +
//   js*4 + e] = V[c = ctg*16 + (lr&15)][j = jc2*32 + js*16 + (lr>>4)*4 + e]
// ---------------------------------------------------------------------------
__global__ __launch_bounds__(512, 2) void proj_kernel(
    const float* __restrict__ sem, const float* __restrict__ str,
    const _Float16* __restrict__ Wh,
    const float* __restrict__ bq, const float* __restrict__ bk,
    const float* __restrict__ bv,
    _Float16* __restrict__ Qh, _Float16* __restrict__ Kh, _Float16* __restrict__ Vh2)
{
    __shared__ __align__(16) _Float16 smem[2 * 64 * CP];   // 66 KB, double-duty
    _Float16* s_x = smem;              // structural staging
    _Float16* s_s = smem + 64 * CP;    // semantic staging

    const int bid = blockIdx.x;
    const int nt6 = bid & 63;
    const int b   = bid >> 6;
    const int n0  = nt6 * 64;
    const int tid = threadIdx.x;
    const int w    = tid >> 6;       // 0..7
    const int lane = tid & 63;
    const int quad = lane >> 4;
    const int l15  = lane & 15;

    const int cnt = (w < 4) ? 3 : 2;
    const int t0  = (w < 4) ? w*3 : 12 + (w-4)*2;

    f32x4 acc[3][4];
    #pragma unroll
    for (int i = 0; i < 3; ++i)
        #pragma unroll
        for (int j = 0; j < 4; ++j) { acc[i][j][0]=0.f; acc[i][j][1]=0.f; acc[i][j][2]=0.f; acc[i][j][3]=0.f; }

    const size_t xbase = (size_t)b * C_ * N_;

    // ---- stage both 64n x 256c tiles, then ONE barrier ----
    #pragma unroll
    for (int r = 0; r < 4; ++r) {
        const int slot = r*512 + tid;
        const int nq = slot & 15;        // n-quad
        const int cp = slot >> 4;        // c-pair 0..127
        const float* p0 = str + xbase + (size_t)(2*cp) * N_ + n0 + nq*4;
        const float4 a4 = *(const float4*)p0;
        const float4 b4 = *(const float4*)(p0 + N_);
        #pragma unroll
        for (int t = 0; t < 4; ++t) {
            half2v hp; hp[0] = (_Float16)a4[t]; hp[1] = (_Float16)b4[t];
            *(half2v*)(s_x + (nq*4 + t)*CP + 2*cp) = hp;
        }
        const float* p1 = sem + xbase + (size_t)(2*cp) * N_ + n0 + nq*4;
        const float4 c4 = *(const float4*)p1;
        const float4 d4 = *(const float4*)(p1 + N_);
        #pragma unroll
        for (int t = 0; t < 4; ++t) {
            half2v hp; hp[0] = (_Float16)c4[t]; hp[1] = (_Float16)d4[t];
            *(half2v*)(s_s + (nq*4 + t)*CP + 2*cp) = hp;
        }
    }
    __syncthreads();

    // ---- compute: Wh A-frags double-buffered across kc ----
    auto afload = [&](half8 (&af)[3], int kc) {
        #pragma unroll
        for (int mi = 0; mi < 3; ++mi)
            if (mi < cnt)
                af[mi] = *(const half8*)(Wh + ((size_t)(((t0+mi)*8 + kc)*16 + l15))*32 + quad*8);
    };
    auto bload = [&](half8 (&bfr)[4], half8 (&sfr)[4], int kc) {
        #pragma unroll
        for (int nt = 0; nt < 4; ++nt)
            bfr[nt] = *(const half8*)(s_x + (nt*16 + l15)*CP + kc*32 + quad*8);
        if (w == 0) {
            #pragma unroll
            for (int nt = 0; nt < 4; ++nt)
                sfr[nt] = *(const half8*)(s_s + (nt*16 + l15)*CP + kc*32 + quad*8);
        }
    };
    auto domfma = [&](const half8 (&af)[3], const half8 (&bfr)[4], const half8 (&sfr)[4]) {
        #pragma unroll
        for (int mi = 0; mi < 3; ++mi) {
            if (mi >= cnt) break;
            const bool useS = (t0 + mi) < 2;   // q uses semantic
            #pragma unroll
            for (int nt = 0; nt < 4; ++nt)
                acc[mi][nt] = __builtin_amdgcn_mfma_f32_16x16x32_f16(
                                  af[mi], useS ? sfr[nt] : bfr[nt], acc[mi][nt], 0, 0, 0);
        }
    };

    half8 afA[3], afB[3];
    afload(afA, 0);
    #pragma unroll 1
    for (int kc2 = 0; kc2 < 4; ++kc2) {
        const int kc = kc2*2;
        half8 bfr[4], sfr[4];
        bload(bfr, sfr, kc);
        afload(afB, kc+1);
        domfma(afA, bfr, sfr);
        half8 bfr2[4], sfr2[4];
        bload(bfr2, sfr2, kc+1);
        if (kc2 < 3) afload(afA, kc+2);
        domfma(afB, bfr2, sfr2);
    }

    // ---- q/k epilogue first (no LDS), then barrier, then V via aliased LDS ----
    #pragma unroll
    for (int mi = 0; mi < 3; ++mi) {
        if (mi >= cnt) break;
        const int t = t0 + mi;
        if (t < 4) {
            const bool isq = (t < 2);
            const int  tt  = isq ? t : (t - 2);
            f32x4 b4 = *(const f32x4*)((isq ? bq : bk) + tt*16 + quad*4);
            _Float16* dst = isq ? Qh : Kh;
            const int dc  = tt*2 + (quad >> 1);
            const int off = (quad & 1) * 4;
            #pragma unroll
            for (int nt = 0; nt < 4; ++nt) {
                const int n = n0 + nt*16 + l15;
                f32x4 a = acc[mi][nt];
                half4v hq;
                hq[0]=(_Float16)(a[0]+b4[0]); hq[1]=(_Float16)(a[1]+b4[1]);
                hq[2]=(_Float16)(a[2]+b4[2]); hq[3]=(_Float16)(a[3]+b4[3]);
                *(half4v*)(dst + ((size_t)(b*4 + dc) * N_ + n) * 8 + off) = hq;
            }
        }
    }
    __syncthreads();   // all waves done reading s_x/s_s; safe to alias

    #pragma unroll
    for (int mi = 0; mi < 3; ++mi) {
        if (mi >= cnt) break;
        const int t = t0 + mi;
        if (t >= 4) {
            const int ctg = t - 4;
            f32x4 b4 = *(const f32x4*)(bv + ctg*16 + quad*4);
            _Float16* sv = smem + (w*3 + mi)*1024;
            #pragma unroll
            for (int nt = 0; nt < 4; ++nt) {
                const int js = nt & 1;
                const int hb = nt >> 1;
                f32x4 a = acc[mi][nt];
                #pragma unroll
                for (int r = 0; r < 4; ++r)
                    sv[hb*512 + ((l15>>2)*16 + quad*4 + r)*8 + js*4 + (l15&3)]
                        = (_Float16)(a[r] + b4[r]);
            }
        }
    }
    // coalesced V stores (per-wave scratch, no extra barrier needed)
    {
        _Float16* vb = Vh2 + (size_t)b * (size_t)N_ * C_;
        const int jc2_0 = n0 >> 5;
        #pragma unroll
        for (int mi = 0; mi < 3; ++mi) {
            if (mi >= cnt) break;
            const int t = t0 + mi;
            if (t >= 4) {
                const int ctg = t - 4;
                const _Float16* sv = smem + (w*3 + mi)*1024;
                #pragma unroll
                for (int hb = 0; hb < 2; ++hb) {
                    half8 vv = *(const half8*)(&sv[hb*512 + lane*8]);
                    *(half8*)(vb + (size_t)(jc2_0 + hb)*8192 + (size_t)ctg*512 + lane*8) = vv;
                }
            }
        }
    }
}

// ---------------------------------------------------------------------------
// Kernel 2: flash attention v14 — 8-wave blocks for 4 waves/SIMD.
// v12/v13 plateaued at ~64us with 2 waves/SIMD: ~23us MFMA + ~27us VALU of
// issue work vs 66us wall = ~40us unfillable stall (serial QK->exp->PV chain
// + L2 V latency, both resident waves in the same phase). v14: 512-thread
// blocks, wave = (wc in 2) x (wj in 4): j-quarter x c-half per wave. Total
// work and L2 traffic unchanged; 2 blocks/CU x 8 waves = 16 waves/CU ->
// cross-wave MFMA/VALU overlap (m114). VGPR 112 fits the 128 cap of
// __launch_bounds__(512,4). Epilogue: 2-round LDS tree over the 4 wj waves.
// XCD-pinned: xcd=bid&7, b=xcd>>1.
// ---------------------------------------------------------------------------
__global__ __launch_bounds__(512, 4) void flash_kernel(
    const _Float16* __restrict__ Qh, const _Float16* __restrict__ Kh,
    const _Float16* __restrict__ Vh2, const float* __restrict__ sem,
    const float* __restrict__ gma, float* __restrict__ out)
{
    __shared__ float s_mp[8*32];
    __shared__ float s_lp[8*32];
    __shared__ __align__(16) float s_red[4][64][64];   // 64 KB

    const int bid = blockIdx.x;
    const int xcd = bid & 7;
    const int b   = xcd >> 1;
    const int i0  = ((xcd & 1)*64 + (bid >> 3)) * 32;
    const int tid = threadIdx.x;
    const int w    = tid >> 6;      // 0..7
    const int lane = tid & 63;
    const int quad = lane >> 4;
    const int l15  = lane & 15;
    const int wc   = w & 1;         // c-half (8 c-tiles)
    const int wj   = w >> 1;        // j-quarter (1024 j)

    // Q B-frags (persistent): B[k=d][n=i]
    const _Float16* qk_base = Qh + (size_t)(b*4 + quad) * N_ * 8;
    const half8 qf0 = *(const half8*)(qk_base + (size_t)(i0 + l15) * 8);
    const half8 qf1 = *(const half8*)(qk_base + (size_t)(i0 + 16 + l15) * 8);

    const _Float16* klane = Kh + ((size_t)(b*4 + quad) * N_ + l15) * 8;
    const _Float16* vl    = Vh2 + (size_t)b * (size_t)N_ * C_
                            + (size_t)(wc*8) * 512 + (size_t)lane * 8;

    // ---- phase 0: exact row max; wave w covers j in [w*512, +512), K dbuf ----
    float mx0 = -3e38f, mx1 = -3e38f;
    {
        half8 kp[4], kn[4];
        auto kl4 = [&](half8 (&kf)[4], int j0) {
            #pragma unroll
            for (int js = 0; js < 4; ++js)
                kf[js] = *(const half8*)(klane + (size_t)(j0 + js*16) * 8);
        };
        auto p0step = [&](const half8 (&kf)[4], half8 (&kfn)[4], int j0, bool more) {
            if (more) kl4(kfn, j0 + 64);
            #pragma unroll
            for (int js = 0; js < 4; ++js) {
                f32x4 z; z[0]=0.f; z[1]=0.f; z[2]=0.f; z[3]=0.f;
                f32x4 s0 = __builtin_amdgcn_mfma_f32_16x16x32_f16(kf[js], qf0, z, 0, 0, 0);
                f32x4 s1 = __builtin_amdgcn_mfma_f32_16x16x32_f16(kf[js], qf1, z, 0, 0, 0);
                #pragma unroll
                for (int r = 0; r < 4; ++r) { mx0 = fmaxf(mx0, s0[r]); mx1 = fmaxf(mx1, s1[r]); }
            }
        };
        kl4(kp, w*512);
        #pragma unroll 1
        for (int it2 = 0; it2 < 4; ++it2) {
            const int j0 = w*512 + it2*128;
            p0step(kp, kn, j0, true);
            p0step(kn, kp, j0 + 64, it2 < 3);
        }
    }
    mx0 = fmaxf(mx0, __shfl_xor(mx0, 16)); mx0 = fmaxf(mx0, __shfl_xor(mx0, 32));
    mx1 = fmaxf(mx1, __shfl_xor(mx1, 16)); mx1 = fmaxf(mx1, __shfl_xor(mx1, 32));
    if (lane < 32) s_mp[w*32 + lane] = (lane < 16) ? mx0 : mx1;
    __syncthreads();
    float mf0 = -3e38f, mf1 = -3e38f;
    #pragma unroll
    for (int ww = 0; ww < 8; ++ww) {
        mf0 = fmaxf(mf0, s_mp[ww*32 + l15]);
        mf1 = fmaxf(mf1, s_mp[ww*32 + 16 + l15]);
    }

    // ---- main loop: j in [wj*1024, +1024), c-tiles [wc*8, +8) ----
    f32x4 acc[8][2];
    #pragma unroll
    for (int ct = 0; ct < 8; ++ct)
        #pragma unroll
        for (int f = 0; f < 2; ++f) { acc[ct][f][0]=0.f; acc[ct][f][1]=0.f; acc[ct][f][2]=0.f; acc[ct][f][3]=0.f; }
    float l0 = 0.f, l1 = 0.f;

    half8 kA[2], kB[2], vA[8], vB[8];

    auto kl2 = [&](half8 (&kf)[2], int j0) {
        kf[0] = *(const half8*)(klane + (size_t)j0 * 8);
        kf[1] = *(const half8*)(klane + (size_t)(j0 + 16) * 8);
    };
    auto vl8 = [&](half8 (&vf)[8], int j0) {
        const _Float16* p = vl + (size_t)(j0 >> 5) * 8192;
        #pragma unroll
        for (int ct = 0; ct < 8; ++ct)
            vf[ct] = *(const half8*)(p + ct*512);
    };
    auto mkp = [](const f32x4& s, float mf, float& lacc) -> half4v {
        float e0 = __expf(s[0]-mf), e1 = __expf(s[1]-mf);
        float e2 = __expf(s[2]-mf), e3 = __expf(s[3]-mf);
        lacc += (e0+e1)+(e2+e3);
        half2v p01 = __builtin_bit_cast(half2v, __builtin_amdgcn_cvt_pkrtz(e0, e1));
        half2v p23 = __builtin_bit_cast(half2v, __builtin_amdgcn_cvt_pkrtz(e2, e3));
        return __builtin_shufflevector(p01, p23, 0, 1, 2, 3);
    };

    auto step = [&](const half8 (&kf)[2], const half8 (&vf)[8],
                    half8 (&kfn)[2], half8 (&vfn)[8], int j0, bool more) {
        f32x4 z; z[0]=0.f; z[1]=0.f; z[2]=0.f; z[3]=0.f;
        f32x4 sf0[2], sf1[2];
        #pragma unroll
        for (int js = 0; js < 2; ++js) {
            sf0[js] = __builtin_amdgcn_mfma_f32_16x16x32_f16(kf[js], qf0, z, 0, 0, 0);
            sf1[js] = __builtin_amdgcn_mfma_f32_16x16x32_f16(kf[js], qf1, z, 0, 0, 0);
        }
        if (more) {                       // full-step-ahead prefetch
            kl2(kfn, j0 + 32);
            vl8(vfn, j0 + 32);
        }
        half4v pa0 = mkp(sf0[0], mf0, l0);
        half4v pb0 = mkp(sf0[1], mf0, l0);
        half4v pa1 = mkp(sf1[0], mf1, l1);
        half4v pb1 = mkp(sf1[1], mf1, l1);
        half8 pcat0 = __builtin_shufflevector(pa0, pb0, 0, 1, 2, 3, 4, 5, 6, 7);
        half8 pcat1 = __builtin_shufflevector(pa1, pb1, 0, 1, 2, 3, 4, 5, 6, 7);
        __builtin_amdgcn_s_setprio(1);
        #pragma unroll
        for (int ct = 0; ct < 8; ++ct) {
            acc[ct][0] = __builtin_amdgcn_mfma_f32_16x16x32_f16(vf[ct], pcat0, acc[ct][0], 0, 0, 0);
            acc[ct][1] = __builtin_amdgcn_mfma_f32_16x16x32_f16(vf[ct], pcat1, acc[ct][1], 0, 0, 0);
        }
        __builtin_amdgcn_s_setprio(0);
    };

    const int jb = wj * 1024;
    kl2(kA, jb);
    vl8(vA, jb);
    #pragma unroll 1
    for (int s2 = 0; s2 < 16; ++s2) {
        const int j0 = jb + s2*64;
        step(kA, vA, kB, vB, j0, true);
        step(kB, vB, kA, vA, j0 + 32, s2 < 15);
    }

    // ---- epilogue: 4-way wj reduction, 2-round LDS tree ----
    l0 += __shfl_xor(l0, 16); l0 += __shfl_xor(l0, 32);
    l1 += __shfl_xor(l1, 16); l1 += __shfl_xor(l1, 32);
    if (lane < 32) s_lp[w*32 + lane] = (lane < 16) ? l0 : l1;

    const int kx = (lane & 7) << 2;   // XOR swizzle keeps b128 16B-aligned
    // Round 1: waves wj>=2 (w>=4) write full acc; partner (same wc, wj-2) sums.
    if (w >= 4) {
        #pragma unroll
        for (int ct = 0; ct < 8; ++ct) {
            *(f32x4*)&s_red[w - 4][lane][(ct*8)     ^ kx] = acc[ct][0];
            *(f32x4*)&s_red[w - 4][lane][(ct*8 + 4) ^ kx] = acc[ct][1];
        }
    }
    __syncthreads();
    if (w < 4) {
        #pragma unroll
        for (int ct = 0; ct < 8; ++ct) {
            f32x4 a0 = *(const f32x4*)&s_red[w][lane][(ct*8)     ^ kx];
            f32x4 a1 = *(const f32x4*)&s_red[w][lane][(ct*8 + 4) ^ kx];
            acc[ct][0] += a0;
            acc[ct][1] += a1;
        }
    }
    __syncthreads();
    // Round 2: w in {0,1} (wj=0) writes acc[4..7]; w in {2,3} (wj=1) writes acc[0..3].
    if (w < 2) {
        #pragma unroll
        for (int t2 = 0; t2 < 4; ++t2) {
            *(f32x4*)&s_red[w][lane][(t2*8)     ^ kx] = acc[4 + t2][0];
            *(f32x4*)&s_red[w][lane][(t2*8 + 4) ^ kx] = acc[4 + t2][1];
        }
    } else if (w < 4) {
        #pragma unroll
        for (int t2 = 0; t2 < 4; ++t2) {
            *(f32x4*)&s_red[w][lane][(t2*8)     ^ kx] = acc[t2][0];
            *(f32x4*)&s_red[w][lane][(t2*8 + 4) ^ kx] = acc[t2][1];
        }
    }
    __syncthreads();

    if (w < 4) {
        // l totals: sum over the 4 wj waves of this wc
        const int mywc = w & 1;
        const float lt0 = s_lp[(mywc)*32 + l15]      + s_lp[(mywc+2)*32 + l15]
                        + s_lp[(mywc+4)*32 + l15]    + s_lp[(mywc+6)*32 + l15];
        const float lt1 = s_lp[(mywc)*32 + 16 + l15] + s_lp[(mywc+2)*32 + 16 + l15]
                        + s_lp[(mywc+4)*32 + 16 + l15] + s_lp[(mywc+6)*32 + 16 + l15];
        const float g = gma[0];
        const float sc0 = g / lt0, sc1 = g / lt1;

        if (w < 2) {
            // own acc[0..3] + partner(w+2) LDS -> c-tiles wc*8 + 0..3
            #pragma unroll
            for (int t2 = 0; t2 < 4; ++t2) {
                f32x4 r0 = acc[t2][0];
                f32x4 r1 = acc[t2][1];
                f32x4 o0 = *(const f32x4*)&s_red[w + 2][lane][(t2*8)     ^ kx];
                f32x4 o1 = *(const f32x4*)&s_red[w + 2][lane][(t2*8 + 4) ^ kx];
                r0 += o0; r1 += o1;
                const int cb0 = (mywc*8 + t2)*16 + quad*4;
                #pragma unroll
                for (int r4 = 0; r4 < 4; ++r4) {
                    const size_t idx = ((size_t)(b*C_ + cb0 + r4)) * N_ + i0 + l15;
                    out[idx]      = r0[r4] * sc0 + sem[idx];
                    out[idx + 16] = r1[r4] * sc1 + sem[idx + 16];
                }
            }
        } else {
            // own acc[4..7] + partner(w-2) LDS -> c-tiles wc*8 + 4..7
            #pragma unroll
            for (int t2 = 0; t2 < 4; ++t2) {
                f32x4 r0 = acc[4 + t2][0];
                f32x4 r1 = acc[4 + t2][1];
                f32x4 o0 = *(const f32x4*)&s_red[w - 2][lane][(t2*8)     ^ kx];
                f32x4 o1 = *(const f32x4*)&s_red[w - 2][lane][(t2*8 + 4) ^ kx];
                r0 += o0; r1 += o1;
                const int cb0 = (mywc*8 + 4 + t2)*16 + quad*4;
                #pragma unroll
                for (int r4 = 0; r4 < 4; ++r4) {
                    const size_t idx = ((size_t)(b*C_ + cb0 + r4)) * N_ + i0 + l15;
                    out[idx]      = r0[r4] * sc0 + sem[idx];
                    out[idx + 16] = r1[r4] * sc1 + sem[idx + 16];
                }
            }
        }
    }
}

extern "C" void kernel_launch(void* const* d_in, const int* in_sizes, int n_in,
                              void* d_out, int out_size, void* d_ws, size_t ws_size,
                              hipStream_t stream) {
    const float* sem = (const float*)d_in[0];
    const float* str = (const float*)d_in[1];
    const float* Wq  = (const float*)d_in[2];
    const float* bq  = (const float*)d_in[3];
    const float* Wk  = (const float*)d_in[4];
    const float* bk  = (const float*)d_in[5];
    const float* Wv  = (const float*)d_in[6];
    const float* bv  = (const float*)d_in[7];
    const float* gma = (const float*)d_in[8];
    float* out = (float*)d_out;

    // Workspace (f16): Qh 1MB | Kh 1MB | Vh2 8MB | Wh 160KB
    _Float16* Qh  = (_Float16*)d_ws;
    _Float16* Kh  = Qh + (size_t)B_*N_*D_;
    _Float16* Vh2 = Kh + (size_t)B_*N_*D_;
    _Float16* Wh  = Vh2 + (size_t)B_*C_*N_;

    hipLaunchKernelGGL(wcvt_kernel, dim3(320), dim3(256), 0, stream, Wq, Wk, Wv, Wh);
    hipLaunchKernelGGL(proj_kernel, dim3(B_*(N_/64)), dim3(512), 0, stream,
                       sem, str, Wh, bq, bk, bv, Qh, Kh, Vh2);
    hipLaunchKernelGGL(flash_kernel, dim3(B_*(N_/32)), dim3(512), 0, stream,
                       Qh, Kh, Vh2, sem, gma, out);
}

// Round 11
// 175.383 us; speedup vs baseline: 3.1116x; 3.1116x over previous
//
#include <hip/hip_runtime.h>

// Problem constants
#define B_   4
#define C_   256
#define N_   4096   // H*W
#define D_   32     // qk projection dim
#define CP   264    // proj s_x row stride (halves): 256 + 8

typedef _Float16 half8  __attribute__((ext_vector_type(8)));
typedef _Float16 half4v __attribute__((ext_vector_type(4)));
typedef _Float16 half2v __attribute__((ext_vector_type(2)));
typedef float    f32x4  __attribute__((ext_vector_type(4)));
typedef int      i32x4  __attribute__((ext_vector_type(4)));

// ---------------------------------------------------------------------------
// Kernel 0: convert W (f32) -> Wh (f16), A-frag layout:
// Wh[((t*8+kc)*16 + row)*32 + kk] = W_t[row][kc*32+kk], t: 0-1 q, 2-3 k, 4-19 v
// ---------------------------------------------------------------------------
__global__ __launch_bounds__(256) void wcvt_kernel(
    const float* __restrict__ Wq, const float* __restrict__ Wk,
    const float* __restrict__ Wv, _Float16* __restrict__ Wh)
{
    const int idx = blockIdx.x * 256 + threadIdx.x;
    const int kk  = idx & 31;
    const int row = (idx >> 5) & 15;
    const int kc  = (idx >> 9) & 7;
    const int t   = idx >> 12;
    const int c   = kc*32 + kk;
    float v;
    if (t < 2)      v = Wq[(t*16 + row)*C_ + c];
    else if (t < 4) v = Wk[((t-2)*16 + row)*C_ + c];
    else            v = Wv[((t-4)*16 + row)*C_ + c];
    Wh[idx] = (_Float16)v;
}

// ---------------------------------------------------------------------------
// Kernel 1: projections v5 (unchanged from round 9).
// Vh2 layout (flash 16B/lane V loads): Vh2[b][jc2*8192 + ctg*512 + lr*8 +
//   js*4 + e] = V[c = ctg*16 + (lr&15)][j = jc2*32 + js*16 + (lr>>4)*4 + e]
// ---------------------------------------------------------------------------
__global__ __launch_bounds__(512, 2) void proj_kernel(
    const float* __restrict__ sem, const float* __restrict__ str,
    const _Float16* __restrict__ Wh,
    const float* __restrict__ bq, const float* __restrict__ bk,
    const float* __restrict__ bv,
    _Float16* __restrict__ Qh, _Float16* __restrict__ Kh, _Float16* __restrict__ Vh2)
{
    __shared__ __align__(16) _Float16 smem[2 * 64 * CP];   // 66 KB, double-duty
    _Float16* s_x = smem;              // structural staging
    _Float16* s_s = smem + 64 * CP;    // semantic staging

    const int bid = blockIdx.x;
    const int nt6 = bid & 63;
    const int b   = bid >> 6;
    const int n0  = nt6 * 64;
    const int tid = threadIdx.x;
    const int w    = tid >> 6;       // 0..7
    const int lane = tid & 63;
    const int quad = lane >> 4;
    const int l15  = lane & 15;

    const int cnt = (w < 4) ? 3 : 2;
    const int t0  = (w < 4) ? w*3 : 12 + (w-4)*2;

    f32x4 acc[3][4];
    #pragma unroll
    for (int i = 0; i < 3; ++i)
        #pragma unroll
        for (int j = 0; j < 4; ++j) { acc[i][j][0]=0.f; acc[i][j][1]=0.f; acc[i][j][2]=0.f; acc[i][j][3]=0.f; }

    const size_t xbase = (size_t)b * C_ * N_;

    // ---- stage both 64n x 256c tiles, then ONE barrier ----
    #pragma unroll
    for (int r = 0; r < 4; ++r) {
        const int slot = r*512 + tid;
        const int nq = slot & 15;        // n-quad
        const int cp = slot >> 4;        // c-pair 0..127
        const float* p0 = str + xbase + (size_t)(2*cp) * N_ + n0 + nq*4;
        const float4 a4 = *(const float4*)p0;
        const float4 b4 = *(const float4*)(p0 + N_);
        #pragma unroll
        for (int t = 0; t < 4; ++t) {
            half2v hp; hp[0] = (_Float16)a4[t]; hp[1] = (_Float16)b4[t];
            *(half2v*)(s_x + (nq*4 + t)*CP + 2*cp) = hp;
        }
        const float* p1 = sem + xbase + (size_t)(2*cp) * N_ + n0 + nq*4;
        const float4 c4 = *(const float4*)p1;
        const float4 d4 = *(const float4*)(p1 + N_);
        #pragma unroll
        for (int t = 0; t < 4; ++t) {
            half2v hp; hp[0] = (_Float16)c4[t]; hp[1] = (_Float16)d4[t];
            *(half2v*)(s_s + (nq*4 + t)*CP + 2*cp) = hp;
        }
    }
    __syncthreads();

    // ---- compute: Wh A-frags double-buffered across kc ----
    auto afload = [&](half8 (&af)[3], int kc) {
        #pragma unroll
        for (int mi = 0; mi < 3; ++mi)
            if (mi < cnt)
                af[mi] = *(const half8*)(Wh + ((size_t)(((t0+mi)*8 + kc)*16 + l15))*32 + quad*8);
    };
    auto bload = [&](half8 (&bfr)[4], half8 (&sfr)[4], int kc) {
        #pragma unroll
        for (int nt = 0; nt < 4; ++nt)
            bfr[nt] = *(const half8*)(s_x + (nt*16 + l15)*CP + kc*32 + quad*8);
        if (w == 0) {
            #pragma unroll
            for (int nt = 0; nt < 4; ++nt)
                sfr[nt] = *(const half8*)(s_s + (nt*16 + l15)*CP + kc*32 + quad*8);
        }
    };
    auto domfma = [&](const half8 (&af)[3], const half8 (&bfr)[4], const half8 (&sfr)[4]) {
        #pragma unroll
        for (int mi = 0; mi < 3; ++mi) {
            if (mi >= cnt) break;
            const bool useS = (t0 + mi) < 2;   // q uses semantic
            #pragma unroll
            for (int nt = 0; nt < 4; ++nt)
                acc[mi][nt] = __builtin_amdgcn_mfma_f32_16x16x32_f16(
                                  af[mi], useS ? sfr[nt] : bfr[nt], acc[mi][nt], 0, 0, 0);
        }
    };

    half8 afA[3], afB[3];
    afload(afA, 0);
    #pragma unroll 1
    for (int kc2 = 0; kc2 < 4; ++kc2) {
        const int kc = kc2*2;
        half8 bfr[4], sfr[4];
        bload(bfr, sfr, kc);
        afload(afB, kc+1);
        domfma(afA, bfr, sfr);
        half8 bfr2[4], sfr2[4];
        bload(bfr2, sfr2, kc+1);
        if (kc2 < 3) afload(afA, kc+2);
        domfma(afB, bfr2, sfr2);
    }

    // ---- q/k epilogue first (no LDS), then barrier, then V via aliased LDS ----
    #pragma unroll
    for (int mi = 0; mi < 3; ++mi) {
        if (mi >= cnt) break;
        const int t = t0 + mi;
        if (t < 4) {
            const bool isq = (t < 2);
            const int  tt  = isq ? t : (t - 2);
            f32x4 b4 = *(const f32x4*)((isq ? bq : bk) + tt*16 + quad*4);
            _Float16* dst = isq ? Qh : Kh;
            const int dc  = tt*2 + (quad >> 1);
            const int off = (quad & 1) * 4;
            #pragma unroll
            for (int nt = 0; nt < 4; ++nt) {
                const int n = n0 + nt*16 + l15;
                f32x4 a = acc[mi][nt];
                half4v hq;
                hq[0]=(_Float16)(a[0]+b4[0]); hq[1]=(_Float16)(a[1]+b4[1]);
                hq[2]=(_Float16)(a[2]+b4[2]); hq[3]=(_Float16)(a[3]+b4[3]);
                *(half4v*)(dst + ((size_t)(b*4 + dc) * N_ + n) * 8 + off) = hq;
            }
        }
    }
    __syncthreads();   // all waves done reading s_x/s_s; safe to alias

    #pragma unroll
    for (int mi = 0; mi < 3; ++mi) {
        if (mi >= cnt) break;
        const int t = t0 + mi;
        if (t >= 4) {
            const int ctg = t - 4;
            f32x4 b4 = *(const f32x4*)(bv + ctg*16 + quad*4);
            _Float16* sv = smem + (w*3 + mi)*1024;
            #pragma unroll
            for (int nt = 0; nt < 4; ++nt) {
                const int js = nt & 1;
                const int hb = nt >> 1;
                f32x4 a = acc[mi][nt];
                #pragma unroll
                for (int r = 0; r < 4; ++r)
                    sv[hb*512 + ((l15>>2)*16 + quad*4 + r)*8 + js*4 + (l15&3)]
                        = (_Float16)(a[r] + b4[r]);
            }
        }
    }
    // coalesced V stores (per-wave scratch, no extra barrier needed)
    {
        _Float16* vb = Vh2 + (size_t)b * (size_t)N_ * C_;
        const int jc2_0 = n0 >> 5;
        #pragma unroll
        for (int mi = 0; mi < 3; ++mi) {
            if (mi >= cnt) break;
            const int t = t0 + mi;
            if (t >= 4) {
                const int ctg = t - 4;
                const _Float16* sv = smem + (w*3 + mi)*1024;
                #pragma unroll
                for (int hb = 0; hb < 2; ++hb) {
                    half8 vv = *(const half8*)(&sv[hb*512 + lane*8]);
                    *(half8*)(vb + (size_t)(jc2_0 + hb)*8192 + (size_t)ctg*512 + lane*8) = vv;
                }
            }
        }
    }
}

// ---------------------------------------------------------------------------
// Kernel 2: flash attention v15 — QBLK=64, LDS-staged K/V, no j-split.
// Roofline: v12's floor was L2 BW (512 blocks x 2.75MB = 1.4GB / 34.5TB/s
// = 41us of the 63.5us wall). v15 halves V traffic: 64 i-rows per block,
// grid=256 (1 block/CU). Waves = (i-frag in 4) x (c-half in 2); j NOT split
// -> each wave owns its 16i x 128c output fully: no acc reduction, no l
// combine. K+V staged once per block into LDS (linear coalesced copies,
// double-buffered, 74KB), loads issued BEFORE compute (T14) so MFMA+exp
// covers L2 latency; ONE barrier per 64-j step. L2: 256 x 2.8MB = 0.72GB.
// XCD-pinned: xcd=bid&7, b=xcd>>1 (image's Vh2+Kh fit 4MB per-XCD L2).
// __launch_bounds__(512,2): empirical VGPR cap 128 (r10: (512,4) caps at 64!).
// ---------------------------------------------------------------------------
__global__ __launch_bounds__(512, 2) void flash_kernel(
    const _Float16* __restrict__ Qh, const _Float16* __restrict__ Kh,
    const _Float16* __restrict__ Vh2, const float* __restrict__ sem,
    const float* __restrict__ gma, float* __restrict__ out)
{
    __shared__ __align__(16) _Float16 sK[2][4*64*8];      // 2 x 4 KB
    __shared__ __align__(16) _Float16 sV[2][2*8192];      // 2 x 32 KB
    __shared__ float s_mp[8*64];                          // 2 KB

    const int bid = blockIdx.x;
    const int xcd = bid & 7;
    const int b   = xcd >> 1;
    const int i0  = ((xcd & 1)*32 + (bid >> 3)) * 64;
    const int tid = threadIdx.x;
    const int w    = tid >> 6;      // 0..7
    const int lane = tid & 63;
    const int quad = lane >> 4;
    const int l15  = lane & 15;
    const int wif  = w >> 1;        // i-frag 0..3
    const int wc   = w & 1;         // c-half (8 c-tiles)

    // Q frags: all 4 needed in phase 0; main loop uses this wave's one.
    const _Float16* qk_base = Qh + (size_t)(b*4 + quad) * N_ * 8;
    half8 qfs[4];
    #pragma unroll
    for (int i = 0; i < 4; ++i)
        qfs[i] = *(const half8*)(qk_base + (size_t)(i0 + i*16 + l15) * 8);

    const _Float16* klane = Kh + ((size_t)(b*4 + quad) * N_ + l15) * 8;

    // ---- phase 0: exact row max; wave w covers j in [w*512, +512), all i ----
    float mx[4];
    #pragma unroll
    for (int i = 0; i < 4; ++i) mx[i] = -3e38f;
    {
        half8 kp[4], kn[4];
        auto kl4 = [&](half8 (&kf)[4], int j0) {
            #pragma unroll
            for (int js = 0; js < 4; ++js)
                kf[js] = *(const half8*)(klane + (size_t)(j0 + js*16) * 8);
        };
        auto p0step = [&](const half8 (&kf)[4], half8 (&kfn)[4], int j0, bool more) {
            if (more) kl4(kfn, j0 + 64);
            #pragma unroll
            for (int js = 0; js < 4; ++js) {
                f32x4 z; z[0]=0.f; z[1]=0.f; z[2]=0.f; z[3]=0.f;
                #pragma unroll
                for (int i = 0; i < 4; ++i) {
                    f32x4 s = __builtin_amdgcn_mfma_f32_16x16x32_f16(kf[js], qfs[i], z, 0, 0, 0);
                    #pragma unroll
                    for (int r = 0; r < 4; ++r) mx[i] = fmaxf(mx[i], s[r]);
                }
            }
        };
        kl4(kp, w*512);
        #pragma unroll 1
        for (int it2 = 0; it2 < 4; ++it2) {
            const int j0 = w*512 + it2*128;
            p0step(kp, kn, j0, true);
            p0step(kn, kp, j0 + 64, it2 < 3);
        }
    }
    #pragma unroll
    for (int i = 0; i < 4; ++i) {
        mx[i] = fmaxf(mx[i], __shfl_xor(mx[i], 16));
        mx[i] = fmaxf(mx[i], __shfl_xor(mx[i], 32));
    }
    {
        const float mv = (quad == 0) ? mx[0] : (quad == 1) ? mx[1] : (quad == 2) ? mx[2] : mx[3];
        s_mp[w*64 + lane] = mv;   // slot (w, quad*16 + l15) = (w, frag=quad, i=l15)
    }
    __syncthreads();
    float mf = -3e38f;
    #pragma unroll
    for (int ww = 0; ww < 8; ++ww)
        mf = fmaxf(mf, s_mp[ww*64 + wif*16 + l15]);

    // this wave's Q frag (constant-select, rule #20)
    const half8 qf = (wif == 0) ? qfs[0] : (wif == 1) ? qfs[1] : (wif == 2) ? qfs[2] : qfs[3];

    // ---- main loop: all j, staged K/V, wave owns (i-frag wif) x (c-half wc) ----
    f32x4 acc[8];
    #pragma unroll
    for (int ct = 0; ct < 8; ++ct) { acc[ct][0]=0.f; acc[ct][1]=0.f; acc[ct][2]=0.f; acc[ct][3]=0.f; }
    float lsum = 0.f;

    const _Float16* vbB = Vh2 + (size_t)b * (size_t)N_ * C_;
    const int kq  = tid >> 6;        // reuse w as K-stage row
    const int kjj = tid & 63;

    i32x4 vr[4]; i32x4 kr;
    auto stage_issue = [&](int j0) {
        const i32x4* vsrc = (const i32x4*)(vbB + (size_t)(j0 >> 5) * 8192);
        #pragma unroll
        for (int r = 0; r < 4; ++r)
            vr[r] = vsrc[r*512 + tid];
        if (tid < 256)
            kr = *(const i32x4*)(Kh + ((size_t)(b*4 + kq) * N_ + j0 + kjj) * 8);
    };
    auto stage_write = [&](int s) {
        i32x4* vd = (i32x4*)sV[s];
        #pragma unroll
        for (int r = 0; r < 4; ++r)
            vd[r*512 + tid] = vr[r];
        if (tid < 256)
            ((i32x4*)sK[s])[tid] = kr;
    };
    auto mkp = [](const f32x4& s, float mfv, float& lacc) -> half4v {
        float e0 = __expf(s[0]-mfv), e1 = __expf(s[1]-mfv);
        float e2 = __expf(s[2]-mfv), e3 = __expf(s[3]-mfv);
        lacc += (e0+e1)+(e2+e3);
        half2v p01 = __builtin_bit_cast(half2v, __builtin_amdgcn_cvt_pkrtz(e0, e1));
        half2v p23 = __builtin_bit_cast(half2v, __builtin_amdgcn_cvt_pkrtz(e2, e3));
        return __builtin_shufflevector(p01, p23, 0, 1, 2, 3);
    };

    // prologue: stage step 0
    stage_issue(0);
    stage_write(0);
    __syncthreads();

    #pragma unroll 1
    for (int t = 0; t < 64; ++t) {
        const int cur = t & 1;
        if (t < 63) stage_issue((t + 1) * 64);   // issue early: hides L2 latency

        // QK^T for this wave's i-frag over the step's 64 j
        half8 kf[4];
        #pragma unroll
        for (int js = 0; js < 4; ++js)
            kf[js] = *(const half8*)(sK[cur] + (quad*64 + js*16 + l15) * 8);
        f32x4 z; z[0]=0.f; z[1]=0.f; z[2]=0.f; z[3]=0.f;
        f32x4 sf[4];
        #pragma unroll
        for (int js = 0; js < 4; ++js)
            sf[js] = __builtin_amdgcn_mfma_f32_16x16x32_f16(kf[js], qf, z, 0, 0, 0);

        half4v p0 = mkp(sf[0], mf, lsum);
        half4v p1 = mkp(sf[1], mf, lsum);
        half4v p2 = mkp(sf[2], mf, lsum);
        half4v p3 = mkp(sf[3], mf, lsum);
        half8 pc0 = __builtin_shufflevector(p0, p1, 0, 1, 2, 3, 4, 5, 6, 7);  // j0..j0+31
        half8 pc1 = __builtin_shufflevector(p2, p3, 0, 1, 2, 3, 4, 5, 6, 7);  // +32..63

        const _Float16* vbase = sV[cur] + (wc*8)*512 + lane*8;
        __builtin_amdgcn_s_setprio(1);
        #pragma unroll
        for (int ct = 0; ct < 8; ++ct) {
            half8 v0 = *(const half8*)(vbase + ct*512);
            half8 v1 = *(const half8*)(vbase + 8192 + ct*512);
            acc[ct] = __builtin_amdgcn_mfma_f32_16x16x32_f16(v0, pc0, acc[ct], 0, 0, 0);
            acc[ct] = __builtin_amdgcn_mfma_f32_16x16x32_f16(v1, pc1, acc[ct], 0, 0, 0);
        }
        __builtin_amdgcn_s_setprio(0);

        if (t < 63) stage_write(cur ^ 1);        // buf cur^1 fully consumed at t-1
        __syncthreads();
    }

    // ---- epilogue: direct stores (wave owns its tile; l complete in-wave) ----
    lsum += __shfl_xor(lsum, 16);
    lsum += __shfl_xor(lsum, 32);
    const float sc = gma[0] / lsum;
    const int irow = i0 + wif*16 + l15;
    #pragma unroll
    for (int ct = 0; ct < 8; ++ct) {
        const int c0 = (wc*8 + ct)*16 + quad*4;
        #pragma unroll
        for (int r4 = 0; r4 < 4; ++r4) {
            const size_t idx = ((size_t)(b*C_ + c0 + r4)) * N_ + irow;
            out[idx] = acc[ct][r4] * sc + sem[idx];
        }
    }
}

extern "C" void kernel_launch(void* const* d_in, const int* in_sizes, int n_in,
                              void* d_out, int out_size, void* d_ws, size_t ws_size,
                              hipStream_t stream) {
    const float* sem = (const float*)d_in[0];
    const float* str = (const float*)d_in[1];
    const float* Wq  = (const float*)d_in[2];
    const float* bq  = (const float*)d_in[3];
    const float* Wk  = (const float*)d_in[4];
    const float* bk  = (const float*)d_in[5];
    const float* Wv  = (const float*)d_in[6];
    const float* bv  = (const float*)d_in[7];
    const float* gma = (const float*)d_in[8];
    float* out = (float*)d_out;

    // Workspace (f16): Qh 1MB | Kh 1MB | Vh2 8MB | Wh 160KB
    _Float16* Qh  = (_Float16*)d_ws;
    _Float16* Kh  = Qh + (size_t)B_*N_*D_;
    _Float16* Vh2 = Kh + (size_t)B_*N_*D_;
    _Float16* Wh  = Vh2 + (size_t)B_*C_*N_;

    hipLaunchKernelGGL(wcvt_kernel, dim3(320), dim3(256), 0, stream, Wq, Wk, Wv, Wh);
    hipLaunchKernelGGL(proj_kernel, dim3(B_*(N_/64)), dim3(512), 0, stream,
                       sem, str, Wh, bq, bk, bv, Qh, Kh, Vh2);
    hipLaunchKernelGGL(flash_kernel, dim3(256), dim3(512), 0, stream,
                       Qh, Kh, Vh2, sem, gma, out);
}

// Round 12
// 157.310 us; speedup vs baseline: 3.4690x; 1.1149x over previous
//
#include <hip/hip_runtime.h>

// Problem constants
#define B_   4
#define C_   256
#define N_   4096   // H*W
#define D_   32     // qk projection dim
#define CP   264    // proj s_x row stride (halves): 256 + 8

typedef _Float16 half8  __attribute__((ext_vector_type(8)));
typedef _Float16 half4v __attribute__((ext_vector_type(4)));
typedef _Float16 half2v __attribute__((ext_vector_type(2)));
typedef float    f32x4  __attribute__((ext_vector_type(4)));

// ---------------------------------------------------------------------------
// Kernel 0: convert W (f32) -> Wh (f16), A-frag layout:
// Wh[((t*8+kc)*16 + row)*32 + kk] = W_t[row][kc*32+kk], t: 0-1 q, 2-3 k, 4-19 v
// ---------------------------------------------------------------------------
__global__ __launch_bounds__(256) void wcvt_kernel(
    const float* __restrict__ Wq, const float* __restrict__ Wk,
    const float* __restrict__ Wv, _Float16* __restrict__ Wh)
{
    const int idx = blockIdx.x * 256 + threadIdx.x;
    const int kk  = idx & 31;
    const int row = (idx >> 5) & 15;
    const int kc  = (idx >> 9) & 7;
    const int t   = idx >> 12;
    const int c   = kc*32 + kk;
    float v;
    if (t < 2)      v = Wq[(t*16 + row)*C_ + c];
    else if (t < 4) v = Wk[((t-2)*16 + row)*C_ + c];
    else            v = Wv[((t-4)*16 + row)*C_ + c];
    Wh[idx] = (_Float16)v;
}

// ---------------------------------------------------------------------------
// Kernel 1: projections v3 (round-4 version, best measured total) —
// merged-h 512-thread blocks, separate V-transpose LDS (114 KB, 1 block/CU).
// Vh2 layout (flash 16B/lane V loads): Vh2[b][jc2*8192 + ctg*512 + lr*8 +
//   js*4 + e] = V[c = ctg*16 + (lr&15)][j = jc2*32 + js*16 + (lr>>4)*4 + e]
// ---------------------------------------------------------------------------
__global__ __launch_bounds__(512, 2) void proj_kernel(
    const float* __restrict__ sem, const float* __restrict__ str,
    const _Float16* __restrict__ Wh,
    const float* __restrict__ bq, const float* __restrict__ bk,
    const float* __restrict__ bv,
    _Float16* __restrict__ Qh, _Float16* __restrict__ Kh, _Float16* __restrict__ Vh2)
{
    __shared__ __align__(16) _Float16 s_x[64 * CP];      // structural, 33 KB
    __shared__ __align__(16) _Float16 s_s[64 * CP];      // semantic,   33 KB
    __shared__ __align__(16) _Float16 s_v[8][3][1024];   // V transpose, 48 KB

    const int bid = blockIdx.x;
    const int nt6 = bid & 63;
    const int b   = bid >> 6;
    const int n0  = nt6 * 64;
    const int tid = threadIdx.x;
    const int w    = tid >> 6;       // 0..7
    const int lane = tid & 63;
    const int quad = lane >> 4;
    const int l15  = lane & 15;

    const int cnt = (w < 4) ? 3 : 2;
    const int t0  = (w < 4) ? w*3 : 12 + (w-4)*2;

    f32x4 acc[3][4];
    #pragma unroll
    for (int i = 0; i < 3; ++i)
        #pragma unroll
        for (int j = 0; j < 4; ++j) { acc[i][j][0]=0.f; acc[i][j][1]=0.f; acc[i][j][2]=0.f; acc[i][j][3]=0.f; }

    const size_t xbase = (size_t)b * C_ * N_;

    // ---- stage both 64n x 256c tiles, then ONE barrier ----
    #pragma unroll
    for (int r = 0; r < 4; ++r) {
        const int slot = r*512 + tid;
        const int nq = slot & 15;        // n-quad
        const int cp = slot >> 4;        // c-pair 0..127
        const float* p0 = str + xbase + (size_t)(2*cp) * N_ + n0 + nq*4;
        const float4 a4 = *(const float4*)p0;
        const float4 b4 = *(const float4*)(p0 + N_);
        #pragma unroll
        for (int t = 0; t < 4; ++t) {
            half2v hp; hp[0] = (_Float16)a4[t]; hp[1] = (_Float16)b4[t];
            *(half2v*)(s_x + (nq*4 + t)*CP + 2*cp) = hp;
        }
        const float* p1 = sem + xbase + (size_t)(2*cp) * N_ + n0 + nq*4;
        const float4 c4 = *(const float4*)p1;
        const float4 d4 = *(const float4*)(p1 + N_);
        #pragma unroll
        for (int t = 0; t < 4; ++t) {
            half2v hp; hp[0] = (_Float16)c4[t]; hp[1] = (_Float16)d4[t];
            *(half2v*)(s_s + (nq*4 + t)*CP + 2*cp) = hp;
        }
    }
    __syncthreads();

    // ---- compute: Wh A-frags double-buffered across kc ----
    auto afload = [&](half8 (&af)[3], int kc) {
        #pragma unroll
        for (int mi = 0; mi < 3; ++mi)
            if (mi < cnt)
                af[mi] = *(const half8*)(Wh + ((size_t)(((t0+mi)*8 + kc)*16 + l15))*32 + quad*8);
    };
    auto bload = [&](half8 (&bfr)[4], half8 (&sfr)[4], int kc) {
        #pragma unroll
        for (int nt = 0; nt < 4; ++nt)
            bfr[nt] = *(const half8*)(s_x + (nt*16 + l15)*CP + kc*32 + quad*8);
        if (w == 0) {
            #pragma unroll
            for (int nt = 0; nt < 4; ++nt)
                sfr[nt] = *(const half8*)(s_s + (nt*16 + l15)*CP + kc*32 + quad*8);
        }
    };
    auto domfma = [&](const half8 (&af)[3], const half8 (&bfr)[4], const half8 (&sfr)[4]) {
        #pragma unroll
        for (int mi = 0; mi < 3; ++mi) {
            if (mi >= cnt) break;
            const bool useS = (t0 + mi) < 2;   // q uses semantic
            #pragma unroll
            for (int nt = 0; nt < 4; ++nt)
                acc[mi][nt] = __builtin_amdgcn_mfma_f32_16x16x32_f16(
                                  af[mi], useS ? sfr[nt] : bfr[nt], acc[mi][nt], 0, 0, 0);
        }
    };

    half8 afA[3], afB[3];
    afload(afA, 0);
    #pragma unroll 1
    for (int kc2 = 0; kc2 < 4; ++kc2) {
        const int kc = kc2*2;
        half8 bfr[4], sfr[4];
        bload(bfr, sfr, kc);
        afload(afB, kc+1);
        domfma(afA, bfr, sfr);
        half8 bfr2[4], sfr2[4];
        bload(bfr2, sfr2, kc+1);
        if (kc2 < 3) afload(afA, kc+2);
        domfma(afB, bfr2, sfr2);
    }

    // ---- epilogue: bias + store. q/k direct; v via per-wave LDS transpose ----
    #pragma unroll
    for (int mi = 0; mi < 3; ++mi) {
        if (mi >= cnt) break;
        const int t = t0 + mi;
        if (t < 4) {
            const bool isq = (t < 2);
            const int  tt  = isq ? t : (t - 2);
            f32x4 b4 = *(const f32x4*)((isq ? bq : bk) + tt*16 + quad*4);
            _Float16* dst = isq ? Qh : Kh;
            const int dc  = tt*2 + (quad >> 1);
            const int off = (quad & 1) * 4;
            #pragma unroll
            for (int nt = 0; nt < 4; ++nt) {
                const int n = n0 + nt*16 + l15;
                f32x4 a = acc[mi][nt];
                half4v hq;
                hq[0]=(_Float16)(a[0]+b4[0]); hq[1]=(_Float16)(a[1]+b4[1]);
                hq[2]=(_Float16)(a[2]+b4[2]); hq[3]=(_Float16)(a[3]+b4[3]);
                *(half4v*)(dst + ((size_t)(b*4 + dc) * N_ + n) * 8 + off) = hq;
            }
        } else {
            const int ctg = t - 4;
            f32x4 b4 = *(const f32x4*)(bv + ctg*16 + quad*4);
            #pragma unroll
            for (int nt = 0; nt < 4; ++nt) {
                const int js = nt & 1;
                const int hb = nt >> 1;
                f32x4 a = acc[mi][nt];
                #pragma unroll
                for (int r = 0; r < 4; ++r)
                    s_v[w][mi][hb*512 + ((l15>>2)*16 + quad*4 + r)*8 + js*4 + (l15&3)]
                        = (_Float16)(a[r] + b4[r]);
            }
        }
    }
    // coalesced V stores (per-wave scratch, no barrier needed)
    {
        _Float16* vb = Vh2 + (size_t)b * (size_t)N_ * C_;
        const int jc2_0 = n0 >> 5;
        #pragma unroll
        for (int mi = 0; mi < 3; ++mi) {
            if (mi >= cnt) break;
            const int t = t0 + mi;
            if (t >= 4) {
                const int ctg = t - 4;
                #pragma unroll
                for (int hb = 0; hb < 2; ++hb) {
                    half8 vv = *(const half8*)(&s_v[w][mi][hb*512 + lane*8]);
                    *(half8*)(vb + (size_t)(jc2_0 + hb)*8192 + (size_t)ctg*512 + lane*8) = vv;
                }
            }
        }
    }
}

// ---------------------------------------------------------------------------
// Kernel 2: flash attention v16 — v12 (proven 63.5us) with prefetch issue
// hoisted to the top of each step (before the QK MFMAs): ~100 extra cycles
// of load-latency cover, zero register cost. Everything else identical.
// QBLK=32, 256-thr blocks, grid=512 (2 blocks/CU). Wave: wc = w&1 (c-half,
// 8 c-tiles), wj = w>>1 (j-half, 2048 j). Full-step K/V register double
// buffer. PV via 16x16x32 (concat P half8 matches Vh2 element order).
// XCD pinning: xcd = bid&7, b = xcd>>1, i0 from (xcd&1, bid>>3) -> each XCD
// streams ONE image's Vh2 (2MB) + Kh (0.25MB), fits 4MB per-XCD L2.
// ---------------------------------------------------------------------------
__global__ __launch_bounds__(256, 2) void flash_kernel(
    const _Float16* __restrict__ Qh, const _Float16* __restrict__ Kh,
    const _Float16* __restrict__ Vh2, const float* __restrict__ sem,
    const float* __restrict__ gma, float* __restrict__ out)
{
    __shared__ float s_mp[4*32];
    __shared__ float s_lp[4*32];
    __shared__ __align__(16) float s_red[4][64][32];   // 32 KB

    const int bid = blockIdx.x;
    const int xcd = bid & 7;
    const int b   = xcd >> 1;
    const int i0  = ((xcd & 1)*64 + (bid >> 3)) * 32;
    const int tid = threadIdx.x;
    const int w    = tid >> 6;
    const int lane = tid & 63;
    const int quad = lane >> 4;
    const int l15  = lane & 15;
    const int wc   = w & 1;
    const int wj   = w >> 1;

    // Q B-frags (persistent): B[k=d][n=i]
    const _Float16* qk_base = Qh + (size_t)(b*4 + quad) * N_ * 8;
    const half8 qf0 = *(const half8*)(qk_base + (size_t)(i0 + l15) * 8);
    const half8 qf1 = *(const half8*)(qk_base + (size_t)(i0 + 16 + l15) * 8);

    const _Float16* klane = Kh + ((size_t)(b*4 + quad) * N_ + l15) * 8;
    const _Float16* vl    = Vh2 + (size_t)b * (size_t)N_ * C_
                            + (size_t)(wc*8) * 512 + (size_t)lane * 8;

    // ---- phase 0: exact row max (wave w covers j in [w*1024, +1024)), K dbuf ----
    float mx0 = -3e38f, mx1 = -3e38f;
    {
        half8 kp[4], kn[4];
        auto kl4 = [&](half8 (&kf)[4], int j0) {
            #pragma unroll
            for (int js = 0; js < 4; ++js)
                kf[js] = *(const half8*)(klane + (size_t)(j0 + js*16) * 8);
        };
        auto p0step = [&](const half8 (&kf)[4], half8 (&kfn)[4], int j0, bool more) {
            if (more) kl4(kfn, j0 + 64);
            #pragma unroll
            for (int js = 0; js < 4; ++js) {
                f32x4 z; z[0]=0.f; z[1]=0.f; z[2]=0.f; z[3]=0.f;
                f32x4 s0 = __builtin_amdgcn_mfma_f32_16x16x32_f16(kf[js], qf0, z, 0, 0, 0);
                f32x4 s1 = __builtin_amdgcn_mfma_f32_16x16x32_f16(kf[js], qf1, z, 0, 0, 0);
                #pragma unroll
                for (int r = 0; r < 4; ++r) { mx0 = fmaxf(mx0, s0[r]); mx1 = fmaxf(mx1, s1[r]); }
            }
        };
        kl4(kp, w*1024);
        #pragma unroll 1
        for (int it2 = 0; it2 < 8; ++it2) {
            const int j0 = w*1024 + it2*128;
            p0step(kp, kn, j0, true);
            p0step(kn, kp, j0 + 64, it2 < 7);
        }
    }
    mx0 = fmaxf(mx0, __shfl_xor(mx0, 16)); mx0 = fmaxf(mx0, __shfl_xor(mx0, 32));
    mx1 = fmaxf(mx1, __shfl_xor(mx1, 16)); mx1 = fmaxf(mx1, __shfl_xor(mx1, 32));
    if (lane < 32) s_mp[w*32 + lane] = (lane < 16) ? mx0 : mx1;
    __syncthreads();
    float mf0 = -3e38f, mf1 = -3e38f;
    #pragma unroll
    for (int ww = 0; ww < 4; ++ww) {
        mf0 = fmaxf(mf0, s_mp[ww*32 + l15]);
        mf1 = fmaxf(mf1, s_mp[ww*32 + 16 + l15]);
    }

    // ---- main loop: j in [wj*2048, +2048), c-tiles [wc*8, +8) ----
    f32x4 acc[8][2];
    #pragma unroll
    for (int ct = 0; ct < 8; ++ct)
        #pragma unroll
        for (int f = 0; f < 2; ++f) { acc[ct][f][0]=0.f; acc[ct][f][1]=0.f; acc[ct][f][2]=0.f; acc[ct][f][3]=0.f; }
    float l0 = 0.f, l1 = 0.f;

    half8 kA[2], kB[2], vA[8], vB[8];

    auto kl2 = [&](half8 (&kf)[2], int j0) {
        kf[0] = *(const half8*)(klane + (size_t)j0 * 8);
        kf[1] = *(const half8*)(klane + (size_t)(j0 + 16) * 8);
    };
    auto vl8 = [&](half8 (&vf)[8], int j0) {
        const _Float16* p = vl + (size_t)(j0 >> 5) * 8192;
        #pragma unroll
        for (int ct = 0; ct < 8; ++ct)
            vf[ct] = *(const half8*)(p + ct*512);
    };
    auto mkp = [](const f32x4& s, float mf, float& lacc) -> half4v {
        float e0 = __expf(s[0]-mf), e1 = __expf(s[1]-mf);
        float e2 = __expf(s[2]-mf), e3 = __expf(s[3]-mf);
        lacc += (e0+e1)+(e2+e3);
        half2v p01 = __builtin_bit_cast(half2v, __builtin_amdgcn_cvt_pkrtz(e0, e1));
        half2v p23 = __builtin_bit_cast(half2v, __builtin_amdgcn_cvt_pkrtz(e2, e3));
        return __builtin_shufflevector(p01, p23, 0, 1, 2, 3);
    };

    auto step = [&](const half8 (&kf)[2], const half8 (&vf)[8],
                    half8 (&kfn)[2], half8 (&vfn)[8], int j0, bool more) {
        if (more) {                       // prefetch issued FIRST (v16 hoist)
            kl2(kfn, j0 + 32);
            vl8(vfn, j0 + 32);
        }
        f32x4 z; z[0]=0.f; z[1]=0.f; z[2]=0.f; z[3]=0.f;
        f32x4 sf0[2], sf1[2];
        #pragma unroll
        for (int js = 0; js < 2; ++js) {
            sf0[js] = __builtin_amdgcn_mfma_f32_16x16x32_f16(kf[js], qf0, z, 0, 0, 0);
            sf1[js] = __builtin_amdgcn_mfma_f32_16x16x32_f16(kf[js], qf1, z, 0, 0, 0);
        }
        half4v pa0 = mkp(sf0[0], mf0, l0);
        half4v pb0 = mkp(sf0[1], mf0, l0);
        half4v pa1 = mkp(sf1[0], mf1, l1);
        half4v pb1 = mkp(sf1[1], mf1, l1);
        half8 pcat0 = __builtin_shufflevector(pa0, pb0, 0, 1, 2, 3, 4, 5, 6, 7);
        half8 pcat1 = __builtin_shufflevector(pa1, pb1, 0, 1, 2, 3, 4, 5, 6, 7);
        __builtin_amdgcn_s_setprio(1);
        #pragma unroll
        for (int ct = 0; ct < 8; ++ct) {
            acc[ct][0] = __builtin_amdgcn_mfma_f32_16x16x32_f16(vf[ct], pcat0, acc[ct][0], 0, 0, 0);
            acc[ct][1] = __builtin_amdgcn_mfma_f32_16x16x32_f16(vf[ct], pcat1, acc[ct][1], 0, 0, 0);
        }
        __builtin_amdgcn_s_setprio(0);
    };

    const int jb = wj * 2048;
    kl2(kA, jb);
    vl8(vA, jb);
    #pragma unroll 1
    for (int s2 = 0; s2 < 32; ++s2) {
        const int j0 = jb + s2*64;
        step(kA, vA, kB, vB, j0, true);
        step(kB, vB, kA, vA, j0 + 32, s2 < 31);
    }

    // ---- epilogue: l-sum over wj pair + single-round acc reduction ----
    l0 += __shfl_xor(l0, 16); l0 += __shfl_xor(l0, 32);
    l1 += __shfl_xor(l1, 16); l1 += __shfl_xor(l1, 32);
    if (lane < 32) s_lp[w*32 + lane] = (lane < 16) ? l0 : l1;

    const int kx = (lane & 7) << 2;   // XOR swizzle keeps b128 16B-aligned
    if (wj == 0) {
        #pragma unroll
        for (int t2 = 0; t2 < 4; ++t2) {
            *(f32x4*)&s_red[w][lane][(t2*8)     ^ kx] = acc[4 + t2][0];
            *(f32x4*)&s_red[w][lane][(t2*8 + 4) ^ kx] = acc[4 + t2][1];
        }
    } else {
        #pragma unroll
        for (int t2 = 0; t2 < 4; ++t2) {
            *(f32x4*)&s_red[w][lane][(t2*8)     ^ kx] = acc[t2][0];
            *(f32x4*)&s_red[w][lane][(t2*8 + 4) ^ kx] = acc[t2][1];
        }
    }
    __syncthreads();

    const float lt0 = s_lp[wc*32 + l15]      + s_lp[64 + wc*32 + l15];
    const float lt1 = s_lp[wc*32 + 16 + l15] + s_lp[64 + wc*32 + 16 + l15];
    const float g = gma[0];
    const float sc0 = g / lt0, sc1 = g / lt1;
    const int wp = w ^ 2;

    if (wj == 0) {
        #pragma unroll
        for (int t2 = 0; t2 < 4; ++t2) {
            f32x4 r0 = *(const f32x4*)&s_red[wp][lane][(t2*8)     ^ kx];
            f32x4 r1 = *(const f32x4*)&s_red[wp][lane][(t2*8 + 4) ^ kx];
            r0 += acc[t2][0];
            r1 += acc[t2][1];
            const int cb0 = (wc*8 + t2)*16 + quad*4;
            #pragma unroll
            for (int r4 = 0; r4 < 4; ++r4) {
                const size_t idx = ((size_t)(b*C_ + cb0 + r4)) * N_ + i0 + l15;
                out[idx]      = r0[r4] * sc0 + sem[idx];
                out[idx + 16] = r1[r4] * sc1 + sem[idx + 16];
            }
        }
    } else {
        #pragma unroll
        for (int t2 = 0; t2 < 4; ++t2) {
            f32x4 r0 = *(const f32x4*)&s_red[wp][lane][(t2*8)     ^ kx];
            f32x4 r1 = *(const f32x4*)&s_red[wp][lane][(t2*8 + 4) ^ kx];
            r0 += acc[4 + t2][0];
            r1 += acc[4 + t2][1];
            const int cb0 = (wc*8 + 4 + t2)*16 + quad*4;
            #pragma unroll
            for (int r4 = 0; r4 < 4; ++r4) {
                const size_t idx = ((size_t)(b*C_ + cb0 + r4)) * N_ + i0 + l15;
                out[idx]      = r0[r4] * sc0 + sem[idx];
                out[idx + 16] = r1[r4] * sc1 + sem[idx + 16];
            }
        }
    }
}

extern "C" void kernel_launch(void* const* d_in, const int* in_sizes, int n_in,
                              void* d_out, int out_size, void* d_ws, size_t ws_size,
                              hipStream_t stream) {
    const float* sem = (const float*)d_in[0];
    const float* str = (const float*)d_in[1];
    const float* Wq  = (const float*)d_in[2];
    const float* bq  = (const float*)d_in[3];
    const float* Wk  = (const float*)d_in[4];
    const float* bk  = (const float*)d_in[5];
    const float* Wv  = (const float*)d_in[6];
    const float* bv  = (const float*)d_in[7];
    const float* gma = (const float*)d_in[8];
    float* out = (float*)d_out;

    // Workspace (f16): Qh 1MB | Kh 1MB | Vh2 8MB | Wh 160KB
    _Float16* Qh  = (_Float16*)d_ws;
    _Float16* Kh  = Qh + (size_t)B_*N_*D_;
    _Float16* Vh2 = Kh + (size_t)B_*N_*D_;
    _Float16* Wh  = Vh2 + (size_t)B_*C_*N_;

    hipLaunchKernelGGL(wcvt_kernel, dim3(320), dim3(256), 0, stream, Wq, Wk, Wv, Wh);
    hipLaunchKernelGGL(proj_kernel, dim3(B_*(N_/64)), dim3(512), 0, stream,
                       sem, str, Wh, bq, bk, bv, Qh, Kh, Vh2);
    hipLaunchKernelGGL(flash_kernel, dim3(B_*(N_/32)), dim3(256), 0, stream,
                       Qh, Kh, Vh2, sem, gma, out);
}